// Round 9
// baseline (427.365 us; speedup 1.0000x reference)
//
#include <hip/hip_runtime.h>

#define B_SZ 2
#define L_SEQ 2048
#define E_DIM 1024
#define NH 16
#define DH 64
#define DFF_DIM 4096
#define ROWS (B_SZ * L_SEQ)  // 4096
#define NCID 80              // KV chunks per (b,h): sum ceil((qt+1)/8), qt<32

typedef __attribute__((ext_vector_type(8))) short short8;
typedef __attribute__((ext_vector_type(4))) float f32x4;

// ---- bf16 <-> f32 helpers ----
__device__ __forceinline__ short f2bf(float f) {
  unsigned u = __builtin_bit_cast(unsigned, f);
  u = (u + 0x7FFFu + ((u >> 16) & 1u)) >> 16;
  return (short)u;
}
__device__ __forceinline__ float bf2f(short s) {
  unsigned u = ((unsigned)(unsigned short)s) << 16;
  return __builtin_bit_cast(float, u);
}
// HW packed f32->bf16 (RNE, matches f2bf): dst = [lo | hi<<16] in one VALU op
__device__ __forceinline__ unsigned cvt_pk_bf16(float lo, float hi) {
  unsigned r;
  asm("v_cvt_pk_bf16_f32 %0, %1, %2" : "=v"(r) : "v"(lo), "v"(hi));
  return r;
}

// ---- exact-erf GELU via A&S 7.1.26 (abs err < 1.5e-7) ----
__device__ __forceinline__ float fast_gelu(float x) {
  float ax = fabsf(x) * 0.70710678118654752f;
  float t = __builtin_amdgcn_rcpf(__builtin_fmaf(0.3275911f, ax, 1.0f));
  float p = t * __builtin_fmaf(
                    t,
                    __builtin_fmaf(
                        t,
                        __builtin_fmaf(t,
                                       __builtin_fmaf(t, 1.061405429f,
                                                      -1.453152027f),
                                       1.421413741f),
                        -0.284496736f),
                    0.254829592f);
  float erf = 1.0f - p * __expf(-ax * ax);
  erf = copysignf(erf, x);
  return 0.5f * x * (1.0f + erf);
}

// ---- async global->LDS 16B copy ----
__device__ __forceinline__ void async_copy16(const void* g, void* l) {
  __builtin_amdgcn_global_load_lds(
      (const __attribute__((address_space(1))) void*)g,
      (__attribute__((address_space(3))) void*)l, 16, 0, 0);
}

// ---- block reduction over 256 threads (4 waves) ----
__device__ __forceinline__ float block_sum256(float v) {
  __shared__ float sbuf[4];
#pragma unroll
  for (int off = 32; off > 0; off >>= 1) v += __shfl_xor(v, off, 64);
  int lane = threadIdx.x & 63, w = threadIdx.x >> 6;
  if (lane == 0) sbuf[w] = v;
  __syncthreads();
  return sbuf[0] + sbuf[1] + sbuf[2] + sbuf[3];
}

// ---- fused prep: weight transposes + rmsnorm(X) ----
// modes: 1 = plain NxK; 2/3 = Bcat 32-col interleave (Ww at +0, Wv at +32)
__global__ __launch_bounds__(256) void prep_all(
    const float* __restrict__ Wqkv, const float* __restrict__ Wo,
    const float* __restrict__ Ww, const float* __restrict__ Wv,
    const float* __restrict__ Wout, const float* __restrict__ X,
    short* __restrict__ Bqkv3, short* __restrict__ WoT,
    short* __restrict__ Bcat, short* __restrict__ WoutT,
    short* __restrict__ H) {
  __shared__ float tile[32][33];
  int b = blockIdx.x;
  if (b < 16384) {
    const float* W;
    short* Wt;
    int K, N, mode, bx, by;
    if (b < 3072) {
      W = Wqkv; Wt = Bqkv3; K = 1024; N = 3072; mode = 1;
      bx = b % 96; by = b / 96;
    } else if (b < 4096) {
      int c = b - 3072;
      W = Wo; Wt = WoT; K = 1024; N = 1024; mode = 1;
      bx = c & 31; by = c >> 5;
    } else if (b < 8192) {
      int c = b - 4096;
      W = Ww; Wt = Bcat; K = 1024; N = 4096; mode = 2;
      bx = c & 127; by = c >> 7;
    } else if (b < 12288) {
      int c = b - 8192;
      W = Wv; Wt = Bcat; K = 1024; N = 4096; mode = 3;
      bx = c & 127; by = c >> 7;
    } else {
      int c = b - 12288;
      W = Wout; Wt = WoutT; K = 4096; N = 1024; mode = 1;
      bx = c & 31; by = c >> 5;
    }
    int n0 = bx * 32, k0 = by * 32;
    int tx = threadIdx.x & 31, ty = threadIdx.x >> 5;
#pragma unroll
    for (int i = 0; i < 4; i++)
      tile[ty + 8 * i][tx] = W[(size_t)(k0 + ty + 8 * i) * N + n0 + tx];
    __syncthreads();
#pragma unroll
    for (int i = 0; i < 4; i++) {
      int n = n0 + ty + 8 * i;
      int orow = (mode == 1)
                     ? n
                     : ((n >> 5) * 64 + (n & 31) + (mode == 3 ? 32 : 0));
      Wt[(size_t)orow * K + k0 + tx] = f2bf(tile[tx][ty + 8 * i]);
    }
  } else {
    size_t row = b - 16384;
    float4 v = ((const float4*)(X + row * E_DIM))[threadIdx.x];
    float ss = v.x * v.x + v.y * v.y + v.z * v.z + v.w * v.w;
    ss = block_sum256(ss);
    float inv = rsqrtf(ss * (1.0f / E_DIM));
    short* h = H + row * E_DIM + (size_t)threadIdx.x * 4;
    h[0] = f2bf(v.x * inv);
    h[1] = f2bf(v.y * inv);
    h[2] = f2bf(v.z * inv);
    h[3] = f2bf(v.w * inv);
  }
}

// ---- fused: X1 = X + p0 + p1 + bias; X2 = X1*(1+1/rms) -> Xout; h2 -> H ----
__global__ __launch_bounds__(256) void resid_rms_fused(
    const float* __restrict__ X, const float* __restrict__ P0,
    const float* __restrict__ P1, const float* __restrict__ bias,
    float* __restrict__ Xout, short* __restrict__ H) {
  size_t row = blockIdx.x;
  int t = threadIdx.x;
  float4 v = ((const float4*)(X + row * E_DIM))[t];
  float4 a = ((const float4*)(P0 + row * E_DIM))[t];
  float4 b = ((const float4*)(P1 + row * E_DIM))[t];
  float4 c = ((const float4*)bias)[t];
  v.x += a.x + b.x + c.x;
  v.y += a.y + b.y + c.y;
  v.z += a.z + b.z + c.z;
  v.w += a.w + b.w + c.w;
  float ss = v.x * v.x + v.y * v.y + v.z * v.z + v.w * v.w;
  ss = block_sum256(ss);
  float inv = rsqrtf(ss * (1.0f / E_DIM));
  float4 o;
  o.x = v.x * (1.0f + inv);
  o.y = v.y * (1.0f + inv);
  o.z = v.z * (1.0f + inv);
  o.w = v.w * (1.0f + inv);
  ((float4*)(Xout + row * E_DIM))[t] = o;
  short* h = H + row * E_DIM + (size_t)t * 4;
  h[0] = f2bf(v.x * inv);
  h[1] = f2bf(v.y * inv);
  h[2] = f2bf(v.z * inv);
  h[3] = f2bf(v.w * inv);
}

// ---- out += p0 + p1 (in place on d_out, which holds X2) ----
__global__ __launch_bounds__(256) void add2_k(const float* __restrict__ P0,
                                              const float* __restrict__ P1,
                                              float* __restrict__ out) {
  size_t i = (size_t)blockIdx.x * 256 + threadIdx.x;
  float4 v = ((const float4*)out)[i];
  float4 a = ((const float4*)P0)[i];
  float4 b = ((const float4*)P1)[i];
  v.x += a.x + b.x;
  v.y += a.y + b.y;
  v.z += a.z + b.z;
  v.w += a.w + b.w;
  ((float4*)out)[i] = v;
}

// ---- GEMM: C(MxN) = A(MxK bf16) @ Bt(NxK bf16)^T, BK=64 twin buffers ----
// epi 4 = f32 partial (split-K via z); epi 6 = QKV 3-way scatter (coalesced
// per-tensor layout; V transposed by the separate v_transp kernel — the
// fused transposed write (r8) scatters 2B stores across 64 cache lines
// per instruction and was reverted).
__global__ __launch_bounds__(256, 2) void gemm_bt(
    const short* __restrict__ A, const short* __restrict__ Bt,
    const float* __restrict__ bias, void* __restrict__ out,
    void* __restrict__ out2, void* __restrict__ out3, int M, int N, int K,
    int epi, int ksplit) {
  __shared__ short smem[128 * 32 * 4];  // As0 Bs0 As1 Bs1 = 32 KB
  short* As0 = smem;
  short* Bs0 = smem + 4096;
  short* As1 = smem + 8192;
  short* Bs1 = smem + 12288;
  int t = threadIdx.x;
  int lane = t & 63;
  int quad = lane >> 4, l16 = lane & 15;
  int wave = t >> 6;
  int wr = wave >> 1, wc = wave & 1;
  int m0 = blockIdx.y * 128, n0 = blockIdx.x * 128;
  int klen = K / ksplit;
  int kstart = blockIdx.z * klen;

  f32x4 acc[4][4];
#pragma unroll
  for (int i = 0; i < 4; i++)
#pragma unroll
    for (int j = 0; j < 4; j++) acc[i][j] = (f32x4){0.f, 0.f, 0.f, 0.f};

  for (int k0 = kstart; k0 < kstart + klen; k0 += 64) {
    __syncthreads();
#pragma unroll
    for (int p = 0; p < 2; p++) {
      int s = p * 256 + t;
      int mm = s >> 2, kk = (s & 3) * 8;
      const short* ag = A + (size_t)(m0 + mm) * K + k0 + kk;
      const short* bg = Bt + (size_t)(n0 + mm) * K + k0 + kk;
      async_copy16(ag, As0 + (size_t)s * 8);
      async_copy16(bg, Bs0 + (size_t)s * 8);
      async_copy16(ag + 32, As1 + (size_t)s * 8);
      async_copy16(bg + 32, Bs1 + (size_t)s * 8);
    }
    __syncthreads();
#pragma unroll
    for (int half = 0; half < 2; half++) {
      const short* As = half ? As1 : As0;
      const short* Bs = half ? Bs1 : Bs0;
      short8 af[4], bfv[4];
#pragma unroll
      for (int i = 0; i < 4; i++) {
        af[i] = *(const short8*)&As[(wr * 64 + i * 16 + l16) * 32 + quad * 8];
        bfv[i] = *(const short8*)&Bs[(wc * 64 + i * 16 + l16) * 32 + quad * 8];
      }
#pragma unroll
      for (int mi = 0; mi < 4; mi++)
#pragma unroll
        for (int ni = 0; ni < 4; ni++)
          acc[mi][ni] = __builtin_amdgcn_mfma_f32_16x16x32_bf16(
              af[mi], bfv[ni], acc[mi][ni], 0, 0, 0);
    }
  }

  if (epi == 5) {
    short* FF = (short*)out;
    int ffbase = blockIdx.x * 64 + wc * 32;
#pragma unroll
    for (int mi = 0; mi < 4; mi++)
#pragma unroll
      for (int ni = 0; ni < 2; ni++)
#pragma unroll
        for (int r = 0; r < 4; r++) {
          int rowl = wr * 64 + mi * 16 + quad * 4 + r;
          float g = fast_gelu(acc[mi][ni][r]);
          FF[(size_t)(m0 + rowl) * DFF_DIM + ffbase + ni * 16 + l16] =
              f2bf(g * acc[mi][ni + 2][r]);
        }
    return;
  }

#pragma unroll
  for (int mi = 0; mi < 4; mi++) {
#pragma unroll
    for (int ni = 0; ni < 4; ni++) {
      int col = n0 + wc * 64 + ni * 16 + l16;
#pragma unroll
      for (int r = 0; r < 4; r++) {
        int row = m0 + wr * 64 + mi * 16 + quad * 4 + r;
        float v = acc[mi][ni][r];
        if (epi == 4) {
          float* po = (float*)out + (size_t)blockIdx.z * ((size_t)M * N);
          po[(size_t)row * N + col] = v;
        } else {  // epi == 6: col = h*192 + ty*64 + d
          v += bias[col];
          int h = col / 192;
          int rem = col - h * 192;
          int ty = rem >> 6, d = rem & 63;
          short* dst = (ty == 0) ? (short*)out
                                 : ((ty == 1) ? (short*)out2 : (short*)out3);
          int bb = row >> 11, l = row & 2047;
          dst[((size_t)(bb * NH + h) * L_SEQ + l) * DH + d] = f2bf(v);
        }
      }
    }
  }
}

// ==== 256x256 8-phase GEMM (T2 swizzle + T3/T4 counted vmcnt + T5) =========
// C(MxN) = A(MxK bf16) @ Bt(NxK bf16)^T.  K multiple of 128 (used with 1024).
// 512 threads = 8 waves (2M x 4N); per-wave output 128x64; BK=64.
// LDS 128 KiB: dbuf{0,1} x {A0,A1,B0,B1} half-tiles of 128rows x 64cols bf16.
// Swizzle: within each 128-B row, 16-B slot s holds source col s^(row&7)
// (pre-swizzled global source, linear global_load_lds dest; reads XOR back).
// Staging rotation (iter j computes tiles t=2j [dbuf0, ph0-3], t+1 [dbuf1,
// ph4-7]); each phase stages ONE half-tile whose readers finished >=1 phase
// ago; vmcnt(4) at ph3/ph7 retires exactly the next tile's 4 half-tiles.
// NOTE: no XCD blockIdx swizzle — grids here are fully co-resident (<=2/CU),
// measured r2: swizzle increased FETCH 51->76 MB and cost +4 us.
// epi: 5 = gated-FFN (Bcat interleave).
__global__ __launch_bounds__(512, 2) void gemm256(
    const short* __restrict__ A, const short* __restrict__ Bt,
    const float* __restrict__ bias, void* __restrict__ out,
    void* __restrict__ out2, void* __restrict__ out3, int M, int N, int K,
    int epi) {
  __shared__ __align__(16) short smem[65536];  // 128 KiB
  (void)M;
  (void)N;
  int t = threadIdx.x;
  int lane = t & 63;
  int quad = lane >> 4, l16 = lane & 15;
  int wave = t >> 6;
  int wr = wave >> 2;  // 0..1 (M)
  int wc = wave & 3;   // 0..3 (N)
  int m0 = blockIdx.y * 256, n0 = blockIdx.x * 256;

  // staging constants: slot u*512+t -> row=slot>>3 (u=1 adds 64), s=t&7
  int row0 = t >> 3;
  int sl = (t & 7) ^ (row0 & 7);  // inverse-swizzled source 16B-slot
  int goff = row0 * K + sl * 8;   // element offset (same for u=0; u=1 +64*K)
  int ldw = t * 16;               // linear LDS byte offset within half-tile
  char* smc = (char*)smem;
  auto stageHT = [&](const short* gsrc, int ldsbase) {
    async_copy16(gsrc + goff, smc + ldsbase + ldw);
    async_copy16(gsrc + goff + (K << 6), smc + ldsbase + 8192 + ldw);
  };

  // ds_read constants
  int swz = (l16 & 7) << 4;
  int colp0 = (quad * 16) ^ swz;         // kh=0 byte col (swizzled)
  int colp1 = (64 + quad * 16) ^ swz;    // kh=1
  const char* aB = smc + wr * 16384 + l16 * 128;
  const char* bB = smc + 32768 + (wc >> 1) * 16384 + (wc & 1) * 8192 +
                   l16 * 128;

  f32x4 acc[8][4];
#pragma unroll
  for (int i = 0; i < 8; i++)
#pragma unroll
    for (int j = 0; j < 4; j++) acc[i][j] = (f32x4){0.f, 0.f, 0.f, 0.f};
  short8 areg[4][2], breg[4][2];

  const short* Am0 = A + (size_t)m0 * K;
  const short* Am1 = A + (size_t)(m0 + 128) * K;
  const short* Bn0 = Bt + (size_t)n0 * K;
  const short* Bn1 = Bt + (size_t)(n0 + 128) * K;

  // prologue: tile0 {A0,A1,B0,B1} -> dbuf0; tile1 {B0,B1} -> dbuf1
  stageHT(Am0, 0);
  stageHT(Am1, 16384);
  stageHT(Bn0, 32768);
  stageHT(Bn1, 49152);
  stageHT(Bn0 + 64, 98304);
  stageHT(Bn1 + 64, 114688);
  asm volatile("s_waitcnt vmcnt(4)" ::: "memory");  // tile0 landed
  __builtin_amdgcn_s_barrier();

  int NJ = K >> 7;  // 2 K-tiles per iteration
  for (int j = 0; j < NJ; ++j) {
    int kb = j << 7;  // k of tile t=2j
    bool lastI = (j == NJ - 1);
#pragma unroll
    for (int ph = 0; ph < 8; ++ph) {
      const int sub = ph & 3;       // quadrant: (mq,nq)=(0,0),(0,1),(1,0),(1,1)
      const int mq = sub >> 1;
      const int nq = sub & 1;
      const int dOff = (ph >> 2) ? 65536 : 0;
      // ds-load register subtile
      if (sub == 0 || sub == 2) {
#pragma unroll
        for (int im = 0; im < 4; ++im) {
          areg[im][0] =
              *(const short8*)(aB + dOff + (mq * 4 + im) * 2048 + colp0);
          areg[im][1] =
              *(const short8*)(aB + dOff + (mq * 4 + im) * 2048 + colp1);
        }
      }
      if (sub <= 1) {
#pragma unroll
        for (int in = 0; in < 2; ++in) {
          breg[nq * 2 + in][0] =
              *(const short8*)(bB + dOff + (nq * 2 + in) * 2048 + colp0);
          breg[nq * 2 + in][1] =
              *(const short8*)(bB + dOff + (nq * 2 + in) * 2048 + colp1);
        }
      }
      // stage one half-tile (region's readers completed >=1 phase ago)
      if (ph == 0) stageHT(Am0 + kb + 64, 65536);           // (t+1).A0
      if (ph == 1) stageHT(Am1 + kb + 64, 65536 + 16384);   // (t+1).A1
      if (!lastI) {
        if (ph == 2) stageHT(Bn0 + kb + 128, 32768);        // (t+2).B0
        if (ph == 3) stageHT(Bn1 + kb + 128, 49152);        // (t+2).B1
        if (ph == 4) stageHT(Am0 + kb + 128, 0);            // (t+2).A0
        if (ph == 5) stageHT(Am1 + kb + 128, 16384);        // (t+2).A1
        if (ph == 6) stageHT(Bn0 + kb + 192, 98304);        // (t+3).B0
        if (ph == 7) stageHT(Bn1 + kb + 192, 114688);       // (t+3).B1
      }
      __builtin_amdgcn_s_barrier();
      asm volatile("s_waitcnt lgkmcnt(0)" ::: "memory");
      __builtin_amdgcn_sched_barrier(0);
      __builtin_amdgcn_s_setprio(1);
#pragma unroll
      for (int im = 0; im < 4; ++im)
#pragma unroll
        for (int in = 0; in < 2; ++in)
#pragma unroll
          for (int kh = 0; kh < 2; ++kh)
            acc[mq * 4 + im][nq * 2 + in] =
                __builtin_amdgcn_mfma_f32_16x16x32_bf16(
                    areg[im][kh], breg[nq * 2 + in][kh],
                    acc[mq * 4 + im][nq * 2 + in], 0, 0, 0);
      __builtin_amdgcn_s_setprio(0);
      if (ph == 3) {
        if (lastI)
          asm volatile("s_waitcnt vmcnt(0)" ::: "memory");
        else
          asm volatile("s_waitcnt vmcnt(4)" ::: "memory");
      }
      if (ph == 7 && !lastI)
        asm volatile("s_waitcnt vmcnt(4)" ::: "memory");
      __builtin_amdgcn_s_barrier();
    }
  }

  if (epi == 5) {
    // gated FFN: group g=(n0+wc*64)/64 -> ff cols g*32 + ni*16 + l16
    short* FF = (short*)out;
    int ffbase = (n0 + wc * 64) >> 1;
#pragma unroll
    for (int mi = 0; mi < 8; ++mi)
#pragma unroll
      for (int ni = 0; ni < 2; ++ni)
#pragma unroll
        for (int r = 0; r < 4; ++r) {
          int rowl = wr * 128 + mi * 16 + quad * 4 + r;
          float g = fast_gelu(acc[mi][ni][r]);
          FF[(size_t)(m0 + rowl) * DFF_DIM + ffbase + ni * 16 + l16] =
              f2bf(g * acc[mi][ni + 2][r]);
        }
    return;
  }
  // epi == 6: QKV scatter, col = h*192 + ty*64 + d
#pragma unroll
  for (int mi = 0; mi < 8; ++mi) {
#pragma unroll
    for (int ni = 0; ni < 4; ++ni) {
      int col = n0 + wc * 64 + ni * 16 + l16;
      float bv = bias[col];
      int h = col / 192;
      int rem = col - h * 192;
      int ty = rem >> 6, d = rem & 63;
      short* dst =
          (ty == 0) ? (short*)out : ((ty == 1) ? (short*)out2 : (short*)out3);
#pragma unroll
      for (int r = 0; r < 4; ++r) {
        int row = m0 + wr * 128 + mi * 16 + quad * 4 + r;
        float v = acc[mi][ni][r] + bv;
        int bb = row >> 11, l = row & 2047;
        dst[((size_t)(bb * NH + h) * L_SEQ + l) * DH + d] = f2bf(v);
      }
    }
  }
}

// ---- V transpose: Vh[bh][l][d] -> VTh[bh][d][l] ----
__global__ __launch_bounds__(256) void v_transp(const short* __restrict__ Vh,
                                                short* __restrict__ VTh) {
  int lt = blockIdx.x, bh = blockIdx.y;
  __shared__ short vtile[64 * 72];
  int t = threadIdx.x;
  int r = t >> 3, c = (t & 7) * 8;
  const short* src = Vh + ((size_t)bh * L_SEQ + lt * 64) * DH;
#pragma unroll
  for (int p = 0; p < 2; p++) {
    int row = r + p * 32;
    short8 vv = *(const short8*)(src + (size_t)row * DH + c);
    *(short8*)&vtile[row * 72 + c] = vv;
  }
  __syncthreads();
#pragma unroll
  for (int p = 0; p < 2; p++) {
    int d = r + p * 32;
    short8 o;
#pragma unroll
    for (int u = 0; u < 8; u++) o[u] = vtile[(c + u) * 72 + d];
    *(short8*)(VTh + ((size_t)bh * DH + d) * L_SEQ + lt * 64 + c) = o;
  }
}

// ---- flash attention, constant-m softmax, split-KV (8-tile chunks) ----
// KVBLK=128 staging; swapped QK^T (S^T = mfma(K,Q)) so each lane owns one
// q-row (q = iw+l16): row-sum is lane-local, P->bf16 packs in registers via
// v_cvt_pk_bf16_f32 (1 op vs ~7 for manual RNE) and redistributes to the PV
// A-fragment with 16 shfl + 8 selects (select AFTER shuffle).
// Split-KV retained: r6 measured the merged (1-block-per-qt) form at 98.7us
// with MfmaUtil 7% from per-CU load imbalance; 2560 balanced blocks win.
__global__ __launch_bounds__(256) void attn_k(const short* __restrict__ Qh,
                                              const short* __restrict__ Kh,
                                              const short* __restrict__ VTh,
                                              float* __restrict__ OP,
                                              float* __restrict__ RS) {
  int cid = blockIdx.x;
  int bh = blockIdx.y;
  int h = bh & 15;
  int qt, ch;
  if (cid < 8) {
    qt = cid; ch = 0;
  } else if (cid < 24) {
    qt = 8 + ((cid - 8) >> 1); ch = (cid - 8) & 1;
  } else if (cid < 48) {
    qt = 16 + (cid - 24) / 3; ch = (cid - 24) % 3;
  } else {
    qt = 24 + ((cid - 48) >> 2); ch = (cid - 48) & 3;
  }
  int t0 = ch * 8;
  int tend = min(t0 + 8, qt + 1);

  int t = threadIdx.x;
  int wave = t >> 6, lane = t & 63;
  int quad = lane >> 4, l16 = lane & 15;

  __shared__ short kt[128 * 72];   // [128 k-rows][64+8 d]
  __shared__ short vt[64 * 136];   // [64 d][128+8 k]

  const float L2E = 1.4426950408889634f;
  const float slope = exp2f(-(1.0f + (7.0f / 15.0f) * (float)h));
  const float slopeL = slope * L2E;  // alibi slope in log2 domain
  int iw = qt * 64 + wave * 16;

  short8 qf[2];
  {
    const short* qp = Qh + ((size_t)bh * L_SEQ + iw + l16) * DH + quad * 8;
    qf[0] = *(const short8*)(qp);
    qf[1] = *(const short8*)(qp + 32);
  }

  f32x4 o[4];
#pragma unroll
  for (int i = 0; i < 4; i++) o[i] = (f32x4){0.f, 0.f, 0.f, 0.f};
  float rs = 0.f;
  const int irow = iw + l16;  // this lane's q row
  const float base_l = -slopeL * (float)irow - 8.0f * L2E;

  int sr = t >> 3, sc = (t & 7) * 8;
  const short* kg = Kh + (size_t)bh * L_SEQ * DH;
  const short* vg = VTh + (size_t)bh * DH * L_SEQ;
  // 2-tile (128-row) register prefetch; overreads past a (b,h) slice land in
  // the adjacent workspace buffer (valid memory, values unused).
  short8 kreg[4], vreg[4];
  auto loadKV = [&](int j0) {
    kreg[0] = *(const short8*)(kg + (size_t)(j0 + sr) * DH + sc);
    kreg[1] = *(const short8*)(kg + (size_t)(j0 + sr + 32) * DH + sc);
    kreg[2] = *(const short8*)(kg + (size_t)(j0 + sr + 64) * DH + sc);
    kreg[3] = *(const short8*)(kg + (size_t)(j0 + sr + 96) * DH + sc);
    vreg[0] = *(const short8*)(vg + (size_t)sr * L_SEQ + j0 + sc);
    vreg[1] = *(const short8*)(vg + (size_t)(sr + 32) * L_SEQ + j0 + sc);
    vreg[2] = *(const short8*)(vg + (size_t)sr * L_SEQ + j0 + 64 + sc);
    vreg[3] = *(const short8*)(vg + (size_t)(sr + 32) * L_SEQ + j0 + 64 + sc);
  };
  loadKV(t0 * 64);

  // shfl source lanes for P redistribution:
  // dest (quad,l16) word wj pulls from lane 2*(quad&1)*16 + (wj>>1)*16 + l16
  const int sA = l16 + ((quad & 1) << 5);  // wj>>1 == 0
  const int sB = sA + 16;                  // wj>>1 == 1

  for (int tp = t0; tp < tend; tp += 2) {
    __syncthreads();
    *(short8*)&kt[sr * 72 + sc] = kreg[0];
    *(short8*)&kt[(sr + 32) * 72 + sc] = kreg[1];
    *(short8*)&kt[(sr + 64) * 72 + sc] = kreg[2];
    *(short8*)&kt[(sr + 96) * 72 + sc] = kreg[3];
    *(short8*)&vt[sr * 136 + sc] = vreg[0];
    *(short8*)&vt[(sr + 32) * 136 + sc] = vreg[1];
    *(short8*)&vt[sr * 136 + 64 + sc] = vreg[2];
    *(short8*)&vt[(sr + 32) * 136 + 64 + sc] = vreg[3];
    __syncthreads();
    if (tp + 2 < tend) loadKV((tp + 2) * 64);
    int te = min(tp + 2, tend);
    for (int tix = tp; tix < te; ++tix) {
      int sub = tix - tp;
      int j0 = tix * 64;
      // S^T[nt]: lane holds q = irow (col=l16), k = j0+nt*16+quad*4+r
      f32x4 s[4];
      __builtin_amdgcn_s_setprio(1);
#pragma unroll
      for (int nt = 0; nt < 4; nt++) {
        f32x4 a = (f32x4){0.f, 0.f, 0.f, 0.f};
#pragma unroll
        for (int ks = 0; ks < 2; ks++) {
          short8 kf = *(const short8*)&kt[(sub * 64 + nt * 16 + l16) * 72 +
                                          ks * 32 + quad * 8];
          a = __builtin_amdgcn_mfma_f32_16x16x32_bf16(kf, qf[ks], a, 0, 0, 0);
        }
        s[nt] = a;
      }
      __builtin_amdgcn_s_setprio(0);
      bool diag = (tix == qt);
      unsigned w[4][2];  // w[nt][i]: bf16 pair k = nt*16+quad*4+2i, +1
#pragma unroll
      for (int nt = 0; nt < 4; nt++) {
        int jb_i = j0 + nt * 16 + quad * 4;
        float jb = __builtin_fmaf(slopeL, (float)jb_i, base_l);
        float pv[4];
#pragma unroll
        for (int r = 0; r < 4; r++) {
          // v2 = log2(e)*(s*0.125 + slope*(j-i) - 8); 0.125*L2E = 0.18033688
          float v = __builtin_fmaf(s[nt][r], 0.18033688011117129f,
                                   jb + slopeL * (float)r);
          if (diag && jb_i + r > irow) v = -1e30f;
          float p = exp2f(v);
          rs += p;
          pv[r] = p;
        }
        w[nt][0] = cvt_pk_bf16(pv[0], pv[1]);
        w[nt][1] = cvt_pk_bf16(pv[2], pv[3]);
      }
      // Redistribute to PV A-frag: pf[ks] word wj holds P[q=l16] pair at
      // k64 = ks*32 + quad*8 + 2*wj, sourced from lane sA (wj<2) / sB (wj>=2)
      // register w[2ks + (quad>>1)][wj&1].  The register index depends on the
      // DESTINATION quad, so shuffle both candidates and select after.
      bool hiq = (quad & 2) != 0;
      union {
        unsigned u[4];
        short8 v;
      } pk0, pk1;
      {
        unsigned x0 = __shfl((int)w[0][0], sA, 64);
        unsigned y0 = __shfl((int)w[1][0], sA, 64);
        pk0.u[0] = hiq ? y0 : x0;
        unsigned x1 = __shfl((int)w[0][1], sA, 64);
        unsigned y1 = __shfl((int)w[1][1], sA, 64);
        pk0.u[1] = hiq ? y1 : x1;
        unsigned x2 = __shfl((int)w[0][0], sB, 64);
        unsigned y2 = __shfl((int)w[1][0], sB, 64);
        pk0.u[2] = hiq ? y2 : x2;
        unsigned x3 = __shfl((int)w[0][1], sB, 64);
        unsigned y3 = __shfl((int)w[1][1], sB, 64);
        pk0.u[3] = hiq ? y3 : x3;
        unsigned z0 = __shfl((int)w[2][0], sA, 64);
        unsigned q0 = __shfl((int)w[3][0], sA, 64);
        pk1.u[0] = hiq ? q0 : z0;
        unsigned z1 = __shfl((int)w[2][1], sA, 64);
        unsigned q1 = __shfl((int)w[3][1], sA, 64);
        pk1.u[1] = hiq ? q1 : z1;
        unsigned z2 = __shfl((int)w[2][0], sB, 64);
        unsigned q2 = __shfl((int)w[3][0], sB, 64);
        pk1.u[2] = hiq ? q2 : z2;
        unsigned z3 = __shfl((int)w[2][1], sB, 64);
        unsigned q3 = __shfl((int)w[3][1], sB, 64);
        pk1.u[3] = hiq ? q3 : z3;
      }
      __builtin_amdgcn_s_setprio(1);
#pragma unroll
      for (int nt = 0; nt < 4; nt++) {
        short8 bv0 = *(const short8*)&vt[(nt * 16 + l16) * 136 + sub * 64 +
                                         quad * 8];
        o[nt] = __builtin_amdgcn_mfma_f32_16x16x32_bf16(pk0.v, bv0, o[nt], 0,
                                                        0, 0);
        short8 bv1 = *(const short8*)&vt[(nt * 16 + l16) * 136 + sub * 64 +
                                         32 + quad * 8];
        o[nt] = __builtin_amdgcn_mfma_f32_16x16x32_bf16(pk1.v, bv1, o[nt], 0,
                                                        0, 0);
      }
      __builtin_amdgcn_s_setprio(0);
    }
  }
  // row-sum: reduce over the 4 quads holding the same q = iw+l16
  rs += __shfl_xor(rs, 16, 64);
  rs += __shfl_xor(rs, 32, 64);
  float* op = OP + ((size_t)bh * NCID + cid) * 64 * 64;
  float* rsp = RS + ((size_t)bh * NCID + cid) * 64;
#pragma unroll
  for (int r = 0; r < 4; r++) {
    int rowl = wave * 16 + quad * 4 + r;
#pragma unroll
    for (int nt = 0; nt < 4; nt++) op[rowl * 64 + nt * 16 + l16] = o[nt][r];
  }
  if (quad == 0) rsp[wave * 16 + l16] = rs;
}

// ---- merge split-KV partials: ctx = sum(O) / sum(l) -> bf16 ----
__global__ __launch_bounds__(256) void attn_merge(const float* __restrict__ OP,
                                                  const float* __restrict__ RS,
                                                  short* __restrict__ ctx) {
  int row = blockIdx.x;
  int b = row >> 11, i = row & 2047;
  int qt = i >> 6, rowin = i & 63;
  int base, nch;
  if (qt < 8) {
    base = qt; nch = 1;
  } else if (qt < 16) {
    base = 8 + 2 * (qt - 8); nch = 2;
  } else if (qt < 24) {
    base = 24 + 3 * (qt - 16); nch = 3;
  } else {
    base = 48 + 4 * (qt - 24); nch = 4;
  }
  int t = threadIdx.x;
  int col = t * 4;
  int h = col >> 6;
  int bh = b * NH + h;
  float4 o = {0.f, 0.f, 0.f, 0.f};
  float l = 0.f;
  for (int s = 0; s < nch; s++) {
    size_t cb = ((size_t)bh * NCID + base + s) * 64 + rowin;
    float4 v = *(const float4*)&OP[cb * 64 + (col & 63)];
    o.x += v.x;
    o.y += v.y;
    o.z += v.z;
    o.w += v.w;
    l += RS[cb];
  }
  float inv = 1.0f / l;
  short* dst = ctx + (size_t)row * (NH * DH) + col;
  dst[0] = f2bf(o.x * inv);
  dst[1] = f2bf(o.y * inv);
  dst[2] = f2bf(o.z * inv);
  dst[3] = f2bf(o.w * inv);
}

extern "C" void kernel_launch(void* const* d_in, const int* in_sizes, int n_in,
                              void* d_out, int out_size, void* d_ws,
                              size_t ws_size, hipStream_t stream) {
  const float* X = (const float*)d_in[0];
  const float* Wqkv = (const float*)d_in[2];
  const float* bqkv = (const float*)d_in[3];
  const float* Wo_sa = (const float*)d_in[4];
  const float* bo_sa = (const float*)d_in[5];
  const float* Ww = (const float*)d_in[12];
  const float* Wv = (const float*)d_in[13];
  const float* Wout = (const float*)d_in[14];

  char* ws = (char*)d_ws;
  auto take = [&](size_t bytes) {
    char* p = ws;
    ws += (bytes + 255) & ~(size_t)255;
    return p;
  };
  short* Bqkv3 = (short*)take((size_t)3072 * 1024 * 2);         // 6 MB
  short* WoT = (short*)take((size_t)E_DIM * E_DIM * 2);         // 2 MB
  short* Bcat = (short*)take((size_t)2 * DFF_DIM * E_DIM * 2);  // 16 MB
  short* WoutT = (short*)take((size_t)E_DIM * DFF_DIM * 2);     // 8 MB
  short* Hbuf = (short*)take((size_t)ROWS * E_DIM * 2);         // 8 MB
  short* Qh = (short*)take((size_t)ROWS * NH * DH * 2);         // 8 MB
  short* Kh = (short*)take((size_t)ROWS * NH * DH * 2);         // 8 MB
  short* Vh = (short*)take((size_t)ROWS * NH * DH * 2);         // 8 MB
  short* VTh = (short*)take((size_t)ROWS * NH * DH * 2);        // 8 MB
  short* CTX = (short*)take((size_t)ROWS * NH * DH * 2);        // 8 MB
  char* big = take((size_t)48 * 1024 * 1024);                   // 48 MB
  // OP (41.9 MB) + RS (0.66 MB) in big[0:42.6]; dead after attn_merge.
  float* OP = (float*)big;
  float* RS = OP + (size_t)B_SZ * NH * NCID * 64 * 64;
  // Pwo (32 MB) then FF (32 MB) reuse big[16:48]:
  float* Pwo = (float*)(big + (size_t)16 * 1024 * 1024);
  short* FF = (short*)Pwo;
  // Wout partials (32 MB) span the dead Qh..VTh region:
  float* Pwout = (float*)Qh;
  (void)ws_size;
  (void)in_sizes;
  (void)n_in;
  (void)out_size;

  dim3 blk(256);
  prep_all<<<16384 + ROWS, blk, 0, stream>>>(Wqkv, Wo_sa, Ww, Wv, Wout, X,
                                             Bqkv3, WoT, Bcat, WoutT, Hbuf);
  // QKV gemm on gemm_bt: 768 blocks = 3/CU (gemm256's 192 blocks left 64
  // CUs idle — r6 analysis)
  gemm_bt<<<dim3(3072 / 128, ROWS / 128), blk, 0, stream>>>(
      Hbuf, Bqkv3, bqkv, Qh, Kh, Vh, ROWS, 3072, 1024, 6, 1);
  v_transp<<<dim3(L_SEQ / 64, B_SZ * NH), blk, 0, stream>>>(Vh, VTh);
  attn_k<<<dim3(NCID, B_SZ * NH), blk, 0, stream>>>(Qh, Kh, VTh, OP, RS);
  attn_merge<<<ROWS, blk, 0, stream>>>(OP, RS, CTX);
  // Wo partials, split-K=2 (512 blocks, 128^2 kernel: N too small for 256^2)
  gemm_bt<<<dim3(1024 / 128, ROWS / 128, 2), blk, 0, stream>>>(
      CTX, WoT, nullptr, Pwo, nullptr, nullptr, ROWS, 1024, 1024, 4, 2);
  // X2 -> d_out; h2 -> Hbuf
  resid_rms_fused<<<ROWS, blk, 0, stream>>>(
      X, Pwo, Pwo + (size_t)ROWS * E_DIM, bo_sa, (float*)d_out, Hbuf);
  // gated FFN -> FF, 8-phase 256^2 tile (512 blocks)
  gemm256<<<dim3(2 * DFF_DIM / 256, ROWS / 256), dim3(512), 0, stream>>>(
      Hbuf, Bcat, nullptr, FF, nullptr, nullptr, ROWS, 2 * DFF_DIM, 1024, 5);
  // Wout partials, split-K=2 (512 blocks)
  gemm_bt<<<dim3(1024 / 128, ROWS / 128, 2), blk, 0, stream>>>(
      FF, WoutT, nullptr, Pwout, nullptr, nullptr, ROWS, 1024, 4096, 4, 2);
  // d_out += p0 + p1
  add2_k<<<ROWS * E_DIM / (256 * 4), blk, 0, stream>>>(
      Pwout, Pwout + (size_t)ROWS * E_DIM, (float*)d_out);
}

// Round 10
// 407.237 us; speedup vs baseline: 1.0494x; 1.0494x over previous
//
#include <hip/hip_runtime.h>

#define B_SZ 2
#define L_SEQ 2048
#define E_DIM 1024
#define NH 16
#define DH 64
#define DFF_DIM 4096
#define ROWS (B_SZ * L_SEQ)  // 4096
#define NCID 80              // KV chunks per (b,h): sum ceil((qt+1)/8), qt<32

typedef __attribute__((ext_vector_type(8))) short short8;
typedef __attribute__((ext_vector_type(4))) float f32x4;

// ---- bf16 <-> f32 helpers ----
__device__ __forceinline__ short f2bf(float f) {
  unsigned u = __builtin_bit_cast(unsigned, f);
  u = (u + 0x7FFFu + ((u >> 16) & 1u)) >> 16;
  return (short)u;
}
__device__ __forceinline__ float bf2f(short s) {
  unsigned u = ((unsigned)(unsigned short)s) << 16;
  return __builtin_bit_cast(float, u);
}
// NOTE: do NOT replace with inline-asm v_cvt_pk_bf16_f32 — measured r9
// (+20us total, fast-state control) and learn_hip m240 (-37% µbench):
// hand-written cvt_pk asm defeats compiler scheduling.  Manual pack:
__device__ __forceinline__ unsigned pack2bf(float lo, float hi) {
  return ((unsigned)(unsigned short)f2bf(hi) << 16) |
         (unsigned)(unsigned short)f2bf(lo);
}

// ---- exact-erf GELU via A&S 7.1.26 (abs err < 1.5e-7) ----
__device__ __forceinline__ float fast_gelu(float x) {
  float ax = fabsf(x) * 0.70710678118654752f;
  float t = __builtin_amdgcn_rcpf(__builtin_fmaf(0.3275911f, ax, 1.0f));
  float p = t * __builtin_fmaf(
                    t,
                    __builtin_fmaf(
                        t,
                        __builtin_fmaf(t,
                                       __builtin_fmaf(t, 1.061405429f,
                                                      -1.453152027f),
                                       1.421413741f),
                        -0.284496736f),
                    0.254829592f);
  float erf = 1.0f - p * __expf(-ax * ax);
  erf = copysignf(erf, x);
  return 0.5f * x * (1.0f + erf);
}

// ---- async global->LDS 16B copy ----
__device__ __forceinline__ void async_copy16(const void* g, void* l) {
  __builtin_amdgcn_global_load_lds(
      (const __attribute__((address_space(1))) void*)g,
      (__attribute__((address_space(3))) void*)l, 16, 0, 0);
}

// ---- block reduction over 256 threads (4 waves) ----
__device__ __forceinline__ float block_sum256(float v) {
  __shared__ float sbuf[4];
#pragma unroll
  for (int off = 32; off > 0; off >>= 1) v += __shfl_xor(v, off, 64);
  int lane = threadIdx.x & 63, w = threadIdx.x >> 6;
  if (lane == 0) sbuf[w] = v;
  __syncthreads();
  return sbuf[0] + sbuf[1] + sbuf[2] + sbuf[3];
}

// ---- fused prep: weight transposes + rmsnorm(X) ----
// modes: 1 = plain NxK; 2/3 = Bcat 32-col interleave (Ww at +0, Wv at +32)
__global__ __launch_bounds__(256) void prep_all(
    const float* __restrict__ Wqkv, const float* __restrict__ Wo,
    const float* __restrict__ Ww, const float* __restrict__ Wv,
    const float* __restrict__ Wout, const float* __restrict__ X,
    short* __restrict__ Bqkv3, short* __restrict__ WoT,
    short* __restrict__ Bcat, short* __restrict__ WoutT,
    short* __restrict__ H) {
  __shared__ float tile[32][33];
  int b = blockIdx.x;
  if (b < 16384) {
    const float* W;
    short* Wt;
    int K, N, mode, bx, by;
    if (b < 3072) {
      W = Wqkv; Wt = Bqkv3; K = 1024; N = 3072; mode = 1;
      bx = b % 96; by = b / 96;
    } else if (b < 4096) {
      int c = b - 3072;
      W = Wo; Wt = WoT; K = 1024; N = 1024; mode = 1;
      bx = c & 31; by = c >> 5;
    } else if (b < 8192) {
      int c = b - 4096;
      W = Ww; Wt = Bcat; K = 1024; N = 4096; mode = 2;
      bx = c & 127; by = c >> 7;
    } else if (b < 12288) {
      int c = b - 8192;
      W = Wv; Wt = Bcat; K = 1024; N = 4096; mode = 3;
      bx = c & 127; by = c >> 7;
    } else {
      int c = b - 12288;
      W = Wout; Wt = WoutT; K = 4096; N = 1024; mode = 1;
      bx = c & 31; by = c >> 5;
    }
    int n0 = bx * 32, k0 = by * 32;
    int tx = threadIdx.x & 31, ty = threadIdx.x >> 5;
#pragma unroll
    for (int i = 0; i < 4; i++)
      tile[ty + 8 * i][tx] = W[(size_t)(k0 + ty + 8 * i) * N + n0 + tx];
    __syncthreads();
#pragma unroll
    for (int i = 0; i < 4; i++) {
      int n = n0 + ty + 8 * i;
      int orow = (mode == 1)
                     ? n
                     : ((n >> 5) * 64 + (n & 31) + (mode == 3 ? 32 : 0));
      Wt[(size_t)orow * K + k0 + tx] = f2bf(tile[tx][ty + 8 * i]);
    }
  } else {
    size_t row = b - 16384;
    float4 v = ((const float4*)(X + row * E_DIM))[threadIdx.x];
    float ss = v.x * v.x + v.y * v.y + v.z * v.z + v.w * v.w;
    ss = block_sum256(ss);
    float inv = rsqrtf(ss * (1.0f / E_DIM));
    short* h = H + row * E_DIM + (size_t)threadIdx.x * 4;
    h[0] = f2bf(v.x * inv);
    h[1] = f2bf(v.y * inv);
    h[2] = f2bf(v.z * inv);
    h[3] = f2bf(v.w * inv);
  }
}

// ---- fused: X1 = X + p0 + p1 + bias; X2 = X1*(1+1/rms) -> Xout; h2 -> H ----
__global__ __launch_bounds__(256) void resid_rms_fused(
    const float* __restrict__ X, const float* __restrict__ P0,
    const float* __restrict__ P1, const float* __restrict__ bias,
    float* __restrict__ Xout, short* __restrict__ H) {
  size_t row = blockIdx.x;
  int t = threadIdx.x;
  float4 v = ((const float4*)(X + row * E_DIM))[t];
  float4 a = ((const float4*)(P0 + row * E_DIM))[t];
  float4 b = ((const float4*)(P1 + row * E_DIM))[t];
  float4 c = ((const float4*)bias)[t];
  v.x += a.x + b.x + c.x;
  v.y += a.y + b.y + c.y;
  v.z += a.z + b.z + c.z;
  v.w += a.w + b.w + c.w;
  float ss = v.x * v.x + v.y * v.y + v.z * v.z + v.w * v.w;
  ss = block_sum256(ss);
  float inv = rsqrtf(ss * (1.0f / E_DIM));
  float4 o;
  o.x = v.x * (1.0f + inv);
  o.y = v.y * (1.0f + inv);
  o.z = v.z * (1.0f + inv);
  o.w = v.w * (1.0f + inv);
  ((float4*)(Xout + row * E_DIM))[t] = o;
  short* h = H + row * E_DIM + (size_t)t * 4;
  h[0] = f2bf(v.x * inv);
  h[1] = f2bf(v.y * inv);
  h[2] = f2bf(v.z * inv);
  h[3] = f2bf(v.w * inv);
}

// ---- out += p0 + p1 (in place on d_out, which holds X2) ----
__global__ __launch_bounds__(256) void add2_k(const float* __restrict__ P0,
                                              const float* __restrict__ P1,
                                              float* __restrict__ out) {
  size_t i = (size_t)blockIdx.x * 256 + threadIdx.x;
  float4 v = ((const float4*)out)[i];
  float4 a = ((const float4*)P0)[i];
  float4 b = ((const float4*)P1)[i];
  v.x += a.x + b.x;
  v.y += a.y + b.y;
  v.z += a.z + b.z;
  v.w += a.w + b.w;
  ((float4*)out)[i] = v;
}

// ---- GEMM: C(MxN) = A(MxK bf16) @ Bt(NxK bf16)^T, BK=64 twin buffers ----
// epi 4 = f32 partial (split-K via z); epi 6 = QKV 3-way scatter (coalesced
// per-tensor layout; V transposed by the separate v_transp kernel — the
// fused transposed write (r8) scatters 2B stores across 64 cache lines
// per instruction and was reverted).
__global__ __launch_bounds__(256, 2) void gemm_bt(
    const short* __restrict__ A, const short* __restrict__ Bt,
    const float* __restrict__ bias, void* __restrict__ out,
    void* __restrict__ out2, void* __restrict__ out3, int M, int N, int K,
    int epi, int ksplit) {
  __shared__ short smem[128 * 32 * 4];  // As0 Bs0 As1 Bs1 = 32 KB
  short* As0 = smem;
  short* Bs0 = smem + 4096;
  short* As1 = smem + 8192;
  short* Bs1 = smem + 12288;
  int t = threadIdx.x;
  int lane = t & 63;
  int quad = lane >> 4, l16 = lane & 15;
  int wave = t >> 6;
  int wr = wave >> 1, wc = wave & 1;
  int m0 = blockIdx.y * 128, n0 = blockIdx.x * 128;
  int klen = K / ksplit;
  int kstart = blockIdx.z * klen;

  f32x4 acc[4][4];
#pragma unroll
  for (int i = 0; i < 4; i++)
#pragma unroll
    for (int j = 0; j < 4; j++) acc[i][j] = (f32x4){0.f, 0.f, 0.f, 0.f};

  for (int k0 = kstart; k0 < kstart + klen; k0 += 64) {
    __syncthreads();
#pragma unroll
    for (int p = 0; p < 2; p++) {
      int s = p * 256 + t;
      int mm = s >> 2, kk = (s & 3) * 8;
      const short* ag = A + (size_t)(m0 + mm) * K + k0 + kk;
      const short* bg = Bt + (size_t)(n0 + mm) * K + k0 + kk;
      async_copy16(ag, As0 + (size_t)s * 8);
      async_copy16(bg, Bs0 + (size_t)s * 8);
      async_copy16(ag + 32, As1 + (size_t)s * 8);
      async_copy16(bg + 32, Bs1 + (size_t)s * 8);
    }
    __syncthreads();
#pragma unroll
    for (int half = 0; half < 2; half++) {
      const short* As = half ? As1 : As0;
      const short* Bs = half ? Bs1 : Bs0;
      short8 af[4], bfv[4];
#pragma unroll
      for (int i = 0; i < 4; i++) {
        af[i] = *(const short8*)&As[(wr * 64 + i * 16 + l16) * 32 + quad * 8];
        bfv[i] = *(const short8*)&Bs[(wc * 64 + i * 16 + l16) * 32 + quad * 8];
      }
#pragma unroll
      for (int mi = 0; mi < 4; mi++)
#pragma unroll
        for (int ni = 0; ni < 4; ni++)
          acc[mi][ni] = __builtin_amdgcn_mfma_f32_16x16x32_bf16(
              af[mi], bfv[ni], acc[mi][ni], 0, 0, 0);
    }
  }

  if (epi == 5) {
    short* FF = (short*)out;
    int ffbase = blockIdx.x * 64 + wc * 32;
#pragma unroll
    for (int mi = 0; mi < 4; mi++)
#pragma unroll
      for (int ni = 0; ni < 2; ni++)
#pragma unroll
        for (int r = 0; r < 4; r++) {
          int rowl = wr * 64 + mi * 16 + quad * 4 + r;
          float g = fast_gelu(acc[mi][ni][r]);
          FF[(size_t)(m0 + rowl) * DFF_DIM + ffbase + ni * 16 + l16] =
              f2bf(g * acc[mi][ni + 2][r]);
        }
    return;
  }

#pragma unroll
  for (int mi = 0; mi < 4; mi++) {
#pragma unroll
    for (int ni = 0; ni < 4; ni++) {
      int col = n0 + wc * 64 + ni * 16 + l16;
#pragma unroll
      for (int r = 0; r < 4; r++) {
        int row = m0 + wr * 64 + mi * 16 + quad * 4 + r;
        float v = acc[mi][ni][r];
        if (epi == 4) {
          float* po = (float*)out + (size_t)blockIdx.z * ((size_t)M * N);
          po[(size_t)row * N + col] = v;
        } else {  // epi == 6: col = h*192 + ty*64 + d
          v += bias[col];
          int h = col / 192;
          int rem = col - h * 192;
          int ty = rem >> 6, d = rem & 63;
          short* dst = (ty == 0) ? (short*)out
                                 : ((ty == 1) ? (short*)out2 : (short*)out3);
          int bb = row >> 11, l = row & 2047;
          dst[((size_t)(bb * NH + h) * L_SEQ + l) * DH + d] = f2bf(v);
        }
      }
    }
  }
}

// ==== 256x256 8-phase GEMM (T2 swizzle + T3/T4 counted vmcnt + T5) =========
// C(MxN) = A(MxK bf16) @ Bt(NxK bf16)^T.  K multiple of 128 (used with 1024).
// 512 threads = 8 waves (2M x 4N); per-wave output 128x64; BK=64.
// LDS 128 KiB: dbuf{0,1} x {A0,A1,B0,B1} half-tiles of 128rows x 64cols bf16.
// Swizzle: within each 128-B row, 16-B slot s holds source col s^(row&7)
// (pre-swizzled global source, linear global_load_lds dest; reads XOR back).
// Staging rotation (iter j computes tiles t=2j [dbuf0, ph0-3], t+1 [dbuf1,
// ph4-7]); each phase stages ONE half-tile whose readers finished >=1 phase
// ago; vmcnt(4) at ph3/ph7 retires exactly the next tile's 4 half-tiles.
// NOTE: no XCD blockIdx swizzle — grids here are fully co-resident (<=2/CU),
// measured r2: swizzle increased FETCH 51->76 MB and cost +4 us.
// epi: 5 = gated-FFN (Bcat interleave).
__global__ __launch_bounds__(512, 2) void gemm256(
    const short* __restrict__ A, const short* __restrict__ Bt,
    const float* __restrict__ bias, void* __restrict__ out,
    void* __restrict__ out2, void* __restrict__ out3, int M, int N, int K,
    int epi) {
  __shared__ __align__(16) short smem[65536];  // 128 KiB
  (void)M;
  (void)N;
  int t = threadIdx.x;
  int lane = t & 63;
  int quad = lane >> 4, l16 = lane & 15;
  int wave = t >> 6;
  int wr = wave >> 2;  // 0..1 (M)
  int wc = wave & 3;   // 0..3 (N)
  int m0 = blockIdx.y * 256, n0 = blockIdx.x * 256;

  // staging constants: slot u*512+t -> row=slot>>3 (u=1 adds 64), s=t&7
  int row0 = t >> 3;
  int sl = (t & 7) ^ (row0 & 7);  // inverse-swizzled source 16B-slot
  int goff = row0 * K + sl * 8;   // element offset (same for u=0; u=1 +64*K)
  int ldw = t * 16;               // linear LDS byte offset within half-tile
  char* smc = (char*)smem;
  auto stageHT = [&](const short* gsrc, int ldsbase) {
    async_copy16(gsrc + goff, smc + ldsbase + ldw);
    async_copy16(gsrc + goff + (K << 6), smc + ldsbase + 8192 + ldw);
  };

  // ds_read constants
  int swz = (l16 & 7) << 4;
  int colp0 = (quad * 16) ^ swz;         // kh=0 byte col (swizzled)
  int colp1 = (64 + quad * 16) ^ swz;    // kh=1
  const char* aB = smc + wr * 16384 + l16 * 128;
  const char* bB = smc + 32768 + (wc >> 1) * 16384 + (wc & 1) * 8192 +
                   l16 * 128;

  f32x4 acc[8][4];
#pragma unroll
  for (int i = 0; i < 8; i++)
#pragma unroll
    for (int j = 0; j < 4; j++) acc[i][j] = (f32x4){0.f, 0.f, 0.f, 0.f};
  short8 areg[4][2], breg[4][2];

  const short* Am0 = A + (size_t)m0 * K;
  const short* Am1 = A + (size_t)(m0 + 128) * K;
  const short* Bn0 = Bt + (size_t)n0 * K;
  const short* Bn1 = Bt + (size_t)(n0 + 128) * K;

  // prologue: tile0 {A0,A1,B0,B1} -> dbuf0; tile1 {B0,B1} -> dbuf1
  stageHT(Am0, 0);
  stageHT(Am1, 16384);
  stageHT(Bn0, 32768);
  stageHT(Bn1, 49152);
  stageHT(Bn0 + 64, 98304);
  stageHT(Bn1 + 64, 114688);
  asm volatile("s_waitcnt vmcnt(4)" ::: "memory");  // tile0 landed
  __builtin_amdgcn_s_barrier();

  int NJ = K >> 7;  // 2 K-tiles per iteration
  for (int j = 0; j < NJ; ++j) {
    int kb = j << 7;  // k of tile t=2j
    bool lastI = (j == NJ - 1);
#pragma unroll
    for (int ph = 0; ph < 8; ++ph) {
      const int sub = ph & 3;       // quadrant: (mq,nq)=(0,0),(0,1),(1,0),(1,1)
      const int mq = sub >> 1;
      const int nq = sub & 1;
      const int dOff = (ph >> 2) ? 65536 : 0;
      // ds-load register subtile
      if (sub == 0 || sub == 2) {
#pragma unroll
        for (int im = 0; im < 4; ++im) {
          areg[im][0] =
              *(const short8*)(aB + dOff + (mq * 4 + im) * 2048 + colp0);
          areg[im][1] =
              *(const short8*)(aB + dOff + (mq * 4 + im) * 2048 + colp1);
        }
      }
      if (sub <= 1) {
#pragma unroll
        for (int in = 0; in < 2; ++in) {
          breg[nq * 2 + in][0] =
              *(const short8*)(bB + dOff + (nq * 2 + in) * 2048 + colp0);
          breg[nq * 2 + in][1] =
              *(const short8*)(bB + dOff + (nq * 2 + in) * 2048 + colp1);
        }
      }
      // stage one half-tile (region's readers completed >=1 phase ago)
      if (ph == 0) stageHT(Am0 + kb + 64, 65536);           // (t+1).A0
      if (ph == 1) stageHT(Am1 + kb + 64, 65536 + 16384);   // (t+1).A1
      if (!lastI) {
        if (ph == 2) stageHT(Bn0 + kb + 128, 32768);        // (t+2).B0
        if (ph == 3) stageHT(Bn1 + kb + 128, 49152);        // (t+2).B1
        if (ph == 4) stageHT(Am0 + kb + 128, 0);            // (t+2).A0
        if (ph == 5) stageHT(Am1 + kb + 128, 16384);        // (t+2).A1
        if (ph == 6) stageHT(Bn0 + kb + 192, 98304);        // (t+3).B0
        if (ph == 7) stageHT(Bn1 + kb + 192, 114688);       // (t+3).B1
      }
      __builtin_amdgcn_s_barrier();
      asm volatile("s_waitcnt lgkmcnt(0)" ::: "memory");
      __builtin_amdgcn_sched_barrier(0);
      __builtin_amdgcn_s_setprio(1);
#pragma unroll
      for (int im = 0; im < 4; ++im)
#pragma unroll
        for (int in = 0; in < 2; ++in)
#pragma unroll
          for (int kh = 0; kh < 2; ++kh)
            acc[mq * 4 + im][nq * 2 + in] =
                __builtin_amdgcn_mfma_f32_16x16x32_bf16(
                    areg[im][kh], breg[nq * 2 + in][kh],
                    acc[mq * 4 + im][nq * 2 + in], 0, 0, 0);
      __builtin_amdgcn_s_setprio(0);
      if (ph == 3) {
        if (lastI)
          asm volatile("s_waitcnt vmcnt(0)" ::: "memory");
        else
          asm volatile("s_waitcnt vmcnt(4)" ::: "memory");
      }
      if (ph == 7 && !lastI)
        asm volatile("s_waitcnt vmcnt(4)" ::: "memory");
      __builtin_amdgcn_s_barrier();
    }
  }

  if (epi == 5) {
    // gated FFN: group g=(n0+wc*64)/64 -> ff cols g*32 + ni*16 + l16
    short* FF = (short*)out;
    int ffbase = (n0 + wc * 64) >> 1;
#pragma unroll
    for (int mi = 0; mi < 8; ++mi)
#pragma unroll
      for (int ni = 0; ni < 2; ++ni)
#pragma unroll
        for (int r = 0; r < 4; ++r) {
          int rowl = wr * 128 + mi * 16 + quad * 4 + r;
          float g = fast_gelu(acc[mi][ni][r]);
          FF[(size_t)(m0 + rowl) * DFF_DIM + ffbase + ni * 16 + l16] =
              f2bf(g * acc[mi][ni + 2][r]);
        }
    return;
  }
  // epi == 6: QKV scatter, col = h*192 + ty*64 + d
#pragma unroll
  for (int mi = 0; mi < 8; ++mi) {
#pragma unroll
    for (int ni = 0; ni < 4; ++ni) {
      int col = n0 + wc * 64 + ni * 16 + l16;
      float bv = bias[col];
      int h = col / 192;
      int rem = col - h * 192;
      int ty = rem >> 6, d = rem & 63;
      short* dst =
          (ty == 0) ? (short*)out : ((ty == 1) ? (short*)out2 : (short*)out3);
#pragma unroll
      for (int r = 0; r < 4; ++r) {
        int row = m0 + wr * 128 + mi * 16 + quad * 4 + r;
        float v = acc[mi][ni][r] + bv;
        int bb = row >> 11, l = row & 2047;
        dst[((size_t)(bb * NH + h) * L_SEQ + l) * DH + d] = f2bf(v);
      }
    }
  }
}

// ---- V transpose: Vh[bh][l][d] -> VTh[bh][d][l] ----
__global__ __launch_bounds__(256) void v_transp(const short* __restrict__ Vh,
                                                short* __restrict__ VTh) {
  int lt = blockIdx.x, bh = blockIdx.y;
  __shared__ short vtile[64 * 72];
  int t = threadIdx.x;
  int r = t >> 3, c = (t & 7) * 8;
  const short* src = Vh + ((size_t)bh * L_SEQ + lt * 64) * DH;
#pragma unroll
  for (int p = 0; p < 2; p++) {
    int row = r + p * 32;
    short8 vv = *(const short8*)(src + (size_t)row * DH + c);
    *(short8*)&vtile[row * 72 + c] = vv;
  }
  __syncthreads();
#pragma unroll
  for (int p = 0; p < 2; p++) {
    int d = r + p * 32;
    short8 o;
#pragma unroll
    for (int u = 0; u < 8; u++) o[u] = vtile[(c + u) * 72 + d];
    *(short8*)(VTh + ((size_t)bh * DH + d) * L_SEQ + lt * 64 + c) = o;
  }
}

// ---- flash attention, constant-m softmax, split-KV (8-tile chunks) ----
// KVBLK=128 staging; swapped QK^T (S^T = mfma(K,Q)) so each lane owns one
// q-row (q = iw+l16): row-sum is lane-local, P->bf16 packs in registers
// (manual pack2bf — see note above) and redistributes to the PV A-fragment
// with 16 shfl + 8 selects (select AFTER shuffle).
// Split-KV retained: r6 measured the merged (1-block-per-qt) form at 98.7us
// with MfmaUtil 7% from per-CU load imbalance; 2560 balanced blocks win.
// OP partials stored as bf16 (halves the OP round-trip traffic; partials
// are pre-normalization, ~2^-8 relative rounding, merged in f32).
__global__ __launch_bounds__(256) void attn_k(const short* __restrict__ Qh,
                                              const short* __restrict__ Kh,
                                              const short* __restrict__ VTh,
                                              short* __restrict__ OP,
                                              float* __restrict__ RS) {
  int cid = blockIdx.x;
  int bh = blockIdx.y;
  int h = bh & 15;
  int qt, ch;
  if (cid < 8) {
    qt = cid; ch = 0;
  } else if (cid < 24) {
    qt = 8 + ((cid - 8) >> 1); ch = (cid - 8) & 1;
  } else if (cid < 48) {
    qt = 16 + (cid - 24) / 3; ch = (cid - 24) % 3;
  } else {
    qt = 24 + ((cid - 48) >> 2); ch = (cid - 48) & 3;
  }
  int t0 = ch * 8;
  int tend = min(t0 + 8, qt + 1);

  int t = threadIdx.x;
  int wave = t >> 6, lane = t & 63;
  int quad = lane >> 4, l16 = lane & 15;

  __shared__ short kt[128 * 72];   // [128 k-rows][64+8 d]
  __shared__ short vt[64 * 136];   // [64 d][128+8 k]

  const float L2E = 1.4426950408889634f;
  const float slope = exp2f(-(1.0f + (7.0f / 15.0f) * (float)h));
  const float slopeL = slope * L2E;  // alibi slope in log2 domain
  int iw = qt * 64 + wave * 16;

  short8 qf[2];
  {
    const short* qp = Qh + ((size_t)bh * L_SEQ + iw + l16) * DH + quad * 8;
    qf[0] = *(const short8*)(qp);
    qf[1] = *(const short8*)(qp + 32);
  }

  f32x4 o[4];
#pragma unroll
  for (int i = 0; i < 4; i++) o[i] = (f32x4){0.f, 0.f, 0.f, 0.f};
  float rs = 0.f;
  const int irow = iw + l16;  // this lane's q row
  const float base_l = -slopeL * (float)irow - 8.0f * L2E;

  int sr = t >> 3, sc = (t & 7) * 8;
  const short* kg = Kh + (size_t)bh * L_SEQ * DH;
  const short* vg = VTh + (size_t)bh * DH * L_SEQ;
  // 2-tile (128-row) register prefetch; overreads past a (b,h) slice land in
  // the adjacent workspace buffer (valid memory, values unused).
  short8 kreg[4], vreg[4];
  auto loadKV = [&](int j0) {
    kreg[0] = *(const short8*)(kg + (size_t)(j0 + sr) * DH + sc);
    kreg[1] = *(const short8*)(kg + (size_t)(j0 + sr + 32) * DH + sc);
    kreg[2] = *(const short8*)(kg + (size_t)(j0 + sr + 64) * DH + sc);
    kreg[3] = *(const short8*)(kg + (size_t)(j0 + sr + 96) * DH + sc);
    vreg[0] = *(const short8*)(vg + (size_t)sr * L_SEQ + j0 + sc);
    vreg[1] = *(const short8*)(vg + (size_t)(sr + 32) * L_SEQ + j0 + sc);
    vreg[2] = *(const short8*)(vg + (size_t)sr * L_SEQ + j0 + 64 + sc);
    vreg[3] = *(const short8*)(vg + (size_t)(sr + 32) * L_SEQ + j0 + 64 + sc);
  };
  loadKV(t0 * 64);

  // shfl source lanes for P redistribution:
  // dest (quad,l16) word wj pulls from lane 2*(quad&1)*16 + (wj>>1)*16 + l16
  const int sA = l16 + ((quad & 1) << 5);  // wj>>1 == 0
  const int sB = sA + 16;                  // wj>>1 == 1

  for (int tp = t0; tp < tend; tp += 2) {
    __syncthreads();
    *(short8*)&kt[sr * 72 + sc] = kreg[0];
    *(short8*)&kt[(sr + 32) * 72 + sc] = kreg[1];
    *(short8*)&kt[(sr + 64) * 72 + sc] = kreg[2];
    *(short8*)&kt[(sr + 96) * 72 + sc] = kreg[3];
    *(short8*)&vt[sr * 136 + sc] = vreg[0];
    *(short8*)&vt[(sr + 32) * 136 + sc] = vreg[1];
    *(short8*)&vt[sr * 136 + 64 + sc] = vreg[2];
    *(short8*)&vt[(sr + 32) * 136 + 64 + sc] = vreg[3];
    __syncthreads();
    if (tp + 2 < tend) loadKV((tp + 2) * 64);
    int te = min(tp + 2, tend);
    for (int tix = tp; tix < te; ++tix) {
      int sub = tix - tp;
      int j0 = tix * 64;
      // S^T[nt]: lane holds q = irow (col=l16), k = j0+nt*16+quad*4+r
      f32x4 s[4];
      __builtin_amdgcn_s_setprio(1);
#pragma unroll
      for (int nt = 0; nt < 4; nt++) {
        f32x4 a = (f32x4){0.f, 0.f, 0.f, 0.f};
#pragma unroll
        for (int ks = 0; ks < 2; ks++) {
          short8 kf = *(const short8*)&kt[(sub * 64 + nt * 16 + l16) * 72 +
                                          ks * 32 + quad * 8];
          a = __builtin_amdgcn_mfma_f32_16x16x32_bf16(kf, qf[ks], a, 0, 0, 0);
        }
        s[nt] = a;
      }
      __builtin_amdgcn_s_setprio(0);
      bool diag = (tix == qt);
      unsigned w[4][2];  // w[nt][i]: bf16 pair k = nt*16+quad*4+2i, +1
#pragma unroll
      for (int nt = 0; nt < 4; nt++) {
        int jb_i = j0 + nt * 16 + quad * 4;
        float jb = __builtin_fmaf(slopeL, (float)jb_i, base_l);
        float pv[4];
#pragma unroll
        for (int r = 0; r < 4; r++) {
          // v2 = log2(e)*(s*0.125 + slope*(j-i) - 8); 0.125*L2E = 0.18033688
          float v = __builtin_fmaf(s[nt][r], 0.18033688011117129f,
                                   jb + slopeL * (float)r);
          if (diag && jb_i + r > irow) v = -1e30f;
          float p = exp2f(v);
          rs += p;
          pv[r] = p;
        }
        w[nt][0] = pack2bf(pv[0], pv[1]);
        w[nt][1] = pack2bf(pv[2], pv[3]);
      }
      // Redistribute to PV A-frag: pf[ks] word wj holds P[q=l16] pair at
      // k64 = ks*32 + quad*8 + 2*wj, sourced from lane sA (wj<2) / sB (wj>=2)
      // register w[2ks + (quad>>1)][wj&1].  The register index depends on the
      // DESTINATION quad, so shuffle both candidates and select after.
      bool hiq = (quad & 2) != 0;
      union {
        unsigned u[4];
        short8 v;
      } pk0, pk1;
      {
        unsigned x0 = __shfl((int)w[0][0], sA, 64);
        unsigned y0 = __shfl((int)w[1][0], sA, 64);
        pk0.u[0] = hiq ? y0 : x0;
        unsigned x1 = __shfl((int)w[0][1], sA, 64);
        unsigned y1 = __shfl((int)w[1][1], sA, 64);
        pk0.u[1] = hiq ? y1 : x1;
        unsigned x2 = __shfl((int)w[0][0], sB, 64);
        unsigned y2 = __shfl((int)w[1][0], sB, 64);
        pk0.u[2] = hiq ? y2 : x2;
        unsigned x3 = __shfl((int)w[0][1], sB, 64);
        unsigned y3 = __shfl((int)w[1][1], sB, 64);
        pk0.u[3] = hiq ? y3 : x3;
        unsigned z0 = __shfl((int)w[2][0], sA, 64);
        unsigned q0 = __shfl((int)w[3][0], sA, 64);
        pk1.u[0] = hiq ? q0 : z0;
        unsigned z1 = __shfl((int)w[2][1], sA, 64);
        unsigned q1 = __shfl((int)w[3][1], sA, 64);
        pk1.u[1] = hiq ? q1 : z1;
        unsigned z2 = __shfl((int)w[2][0], sB, 64);
        unsigned q2 = __shfl((int)w[3][0], sB, 64);
        pk1.u[2] = hiq ? q2 : z2;
        unsigned z3 = __shfl((int)w[2][1], sB, 64);
        unsigned q3 = __shfl((int)w[3][1], sB, 64);
        pk1.u[3] = hiq ? q3 : z3;
      }
      __builtin_amdgcn_s_setprio(1);
#pragma unroll
      for (int nt = 0; nt < 4; nt++) {
        short8 bv0 = *(const short8*)&vt[(nt * 16 + l16) * 136 + sub * 64 +
                                         quad * 8];
        o[nt] = __builtin_amdgcn_mfma_f32_16x16x32_bf16(pk0.v, bv0, o[nt], 0,
                                                        0, 0);
        short8 bv1 = *(const short8*)&vt[(nt * 16 + l16) * 136 + sub * 64 +
                                         32 + quad * 8];
        o[nt] = __builtin_amdgcn_mfma_f32_16x16x32_bf16(pk1.v, bv1, o[nt], 0,
                                                        0, 0);
      }
      __builtin_amdgcn_s_setprio(0);
    }
  }
  // row-sum: reduce over the 4 quads holding the same q = iw+l16
  rs += __shfl_xor(rs, 16, 64);
  rs += __shfl_xor(rs, 32, 64);
  short* op = OP + ((size_t)bh * NCID + cid) * 64 * 64;
  float* rsp = RS + ((size_t)bh * NCID + cid) * 64;
#pragma unroll
  for (int r = 0; r < 4; r++) {
    int rowl = wave * 16 + quad * 4 + r;
#pragma unroll
    for (int nt = 0; nt < 4; nt++)
      op[rowl * 64 + nt * 16 + l16] = f2bf(o[nt][r]);
  }
  if (quad == 0) rsp[wave * 16 + l16] = rs;
}

// ---- merge split-KV partials: ctx = sum(O) / sum(l) -> bf16 ----
__global__ __launch_bounds__(256) void attn_merge(const short* __restrict__ OP,
                                                  const float* __restrict__ RS,
                                                  short* __restrict__ ctx) {
  int row = blockIdx.x;
  int b = row >> 11, i = row & 2047;
  int qt = i >> 6, rowin = i & 63;
  int base, nch;
  if (qt < 8) {
    base = qt; nch = 1;
  } else if (qt < 16) {
    base = 8 + 2 * (qt - 8); nch = 2;
  } else if (qt < 24) {
    base = 24 + 3 * (qt - 16); nch = 3;
  } else {
    base = 48 + 4 * (qt - 24); nch = 4;
  }
  int t = threadIdx.x;
  int col = t * 4;
  int h = col >> 6;
  int bh = b * NH + h;
  float4 o = {0.f, 0.f, 0.f, 0.f};
  float l = 0.f;
  for (int s = 0; s < nch; s++) {
    size_t cb = ((size_t)bh * NCID + base + s) * 64 + rowin;
    const short* pp = &OP[cb * 64 + (col & 63)];
    short4 v = *(const short4*)pp;
    o.x += bf2f(v.x);
    o.y += bf2f(v.y);
    o.z += bf2f(v.z);
    o.w += bf2f(v.w);
    l += RS[cb];
  }
  float inv = 1.0f / l;
  short* dst = ctx + (size_t)row * (NH * DH) + col;
  dst[0] = f2bf(o.x * inv);
  dst[1] = f2bf(o.y * inv);
  dst[2] = f2bf(o.z * inv);
  dst[3] = f2bf(o.w * inv);
}

extern "C" void kernel_launch(void* const* d_in, const int* in_sizes, int n_in,
                              void* d_out, int out_size, void* d_ws,
                              size_t ws_size, hipStream_t stream) {
  const float* X = (const float*)d_in[0];
  const float* Wqkv = (const float*)d_in[2];
  const float* bqkv = (const float*)d_in[3];
  const float* Wo_sa = (const float*)d_in[4];
  const float* bo_sa = (const float*)d_in[5];
  const float* Ww = (const float*)d_in[12];
  const float* Wv = (const float*)d_in[13];
  const float* Wout = (const float*)d_in[14];

  char* ws = (char*)d_ws;
  auto take = [&](size_t bytes) {
    char* p = ws;
    ws += (bytes + 255) & ~(size_t)255;
    return p;
  };
  short* Bqkv3 = (short*)take((size_t)3072 * 1024 * 2);         // 6 MB
  short* WoT = (short*)take((size_t)E_DIM * E_DIM * 2);         // 2 MB
  short* Bcat = (short*)take((size_t)2 * DFF_DIM * E_DIM * 2);  // 16 MB
  short* WoutT = (short*)take((size_t)E_DIM * DFF_DIM * 2);     // 8 MB
  short* Hbuf = (short*)take((size_t)ROWS * E_DIM * 2);         // 8 MB
  short* Qh = (short*)take((size_t)ROWS * NH * DH * 2);         // 8 MB
  short* Kh = (short*)take((size_t)ROWS * NH * DH * 2);         // 8 MB
  short* Vh = (short*)take((size_t)ROWS * NH * DH * 2);         // 8 MB
  short* VTh = (short*)take((size_t)ROWS * NH * DH * 2);        // 8 MB
  short* CTX = (short*)take((size_t)ROWS * NH * DH * 2);        // 8 MB
  char* big = take((size_t)48 * 1024 * 1024);                   // 48 MB
  // OP bf16 (21.0 MB) + RS (0.66 MB) in big[0:21.7]; dead after attn_merge.
  short* OP = (short*)big;
  float* RS = (float*)(big + (size_t)B_SZ * NH * NCID * 64 * 64 * 2);
  // Pwo (32 MB) then FF (32 MB) reuse big[16:48] (overlap with OP tail is
  // fine: OP dead before Pwo is written):
  float* Pwo = (float*)(big + (size_t)16 * 1024 * 1024);
  short* FF = (short*)Pwo;
  // Wout partials (32 MB) span the dead Qh..VTh region:
  float* Pwout = (float*)Qh;
  (void)ws_size;
  (void)in_sizes;
  (void)n_in;
  (void)out_size;

  dim3 blk(256);
  prep_all<<<16384 + ROWS, blk, 0, stream>>>(Wqkv, Wo_sa, Ww, Wv, Wout, X,
                                             Bqkv3, WoT, Bcat, WoutT, Hbuf);
  // QKV gemm on gemm_bt: 768 blocks = 3/CU (gemm256's 192 blocks left 64
  // CUs idle — r6 analysis)
  gemm_bt<<<dim3(3072 / 128, ROWS / 128), blk, 0, stream>>>(
      Hbuf, Bqkv3, bqkv, Qh, Kh, Vh, ROWS, 3072, 1024, 6, 1);
  v_transp<<<dim3(L_SEQ / 64, B_SZ * NH), blk, 0, stream>>>(Vh, VTh);
  attn_k<<<dim3(NCID, B_SZ * NH), blk, 0, stream>>>(Qh, Kh, VTh, OP, RS);
  attn_merge<<<ROWS, blk, 0, stream>>>(OP, RS, CTX);
  // Wo partials, split-K=2 (512 blocks, 128^2 kernel: N too small for 256^2)
  gemm_bt<<<dim3(1024 / 128, ROWS / 128, 2), blk, 0, stream>>>(
      CTX, WoT, nullptr, Pwo, nullptr, nullptr, ROWS, 1024, 1024, 4, 2);
  // X2 -> d_out; h2 -> Hbuf
  resid_rms_fused<<<ROWS, blk, 0, stream>>>(
      X, Pwo, Pwo + (size_t)ROWS * E_DIM, bo_sa, (float*)d_out, Hbuf);
  // gated FFN -> FF, 8-phase 256^2 tile (512 blocks)
  gemm256<<<dim3(2 * DFF_DIM / 256, ROWS / 256), dim3(512), 0, stream>>>(
      Hbuf, Bcat, nullptr, FF, nullptr, nullptr, ROWS, 2 * DFF_DIM, 1024, 5);
  // Wout partials, split-K=2 (512 blocks)
  gemm_bt<<<dim3(1024 / 128, ROWS / 128, 2), blk, 0, stream>>>(
      FF, WoutT, nullptr, Pwout, nullptr, nullptr, ROWS, 1024, 4096, 4, 2);
  // d_out += p0 + p1
  add2_k<<<ROWS * E_DIM / (256 * 4), blk, 0, stream>>>(
      Pwout, Pwout + (size_t)ROWS * E_DIM, (float*)d_out);
}